// Round 12
// baseline (571.075 us; speedup 1.0000x reference)
//
#include <hip/hip_runtime.h>
#include <hip/hip_bf16.h>

#define N    8192
#define INF  256
#define OUTF 128
#define ALPHA 0.2f
#define JS   8               // j-split across blockIdx.y
#define NTS  (N / JS / 32)   // 32 K-steps per block

typedef __attribute__((ext_vector_type(8))) short bf16x8;
typedef __attribute__((ext_vector_type(4))) float f32x4;

__device__ __forceinline__ unsigned short f2bf(float x) {
    union { float f; unsigned u; } v; v.f = x;
    unsigned r = v.u + 0x7fff + ((v.u >> 16) & 1);   // RNE
    return (unsigned short)(r >> 16);
}

// async global->LDS, 16 B per lane (wave-uniform LDS base + lane*16)
__device__ __forceinline__ void gll16(const void* g, void* l) {
    __builtin_amdgcn_global_load_lds(
        (const __attribute__((address_space(1))) unsigned*)g,
        (__attribute__((address_space(3))) unsigned*)l, 16, 0, 0);
}

// ---------------- Kernel 0+1 fused ------------------------------------------
// Blocks [0,1024): k1 body — WhT_b = blocked bf16 (h@W)^T ; f1 ; f2.
// Blocks [1024,3072): k0 body — ballot bit-pack adj (268 MB -> 8 MB),
// perfectly coalesced reads, __ballot gives 64 bits in bitmask order.
__global__ __launch_bounds__(256) void k01_prep(
        const int* __restrict__ adj, unsigned* __restrict__ bits,
        const float* __restrict__ h, const float* __restrict__ W,
        const float* __restrict__ a,
        unsigned short* __restrict__ WhTb, float* __restrict__ f1, float* __restrict__ f2) {
    __shared__ float hs[8][INF];          // 8 KB (k1 blocks only)
    const int t = threadIdx.x;

    if (blockIdx.x >= 1024) {
        const int pb = blockIdx.x - 1024;         // 0..2047
        const int w  = t >> 6;
        const int ln = t & 63;
        const size_t wi0 = ((size_t)pb * 4 + w) * 32;   // wave's first wave-iter
        #pragma unroll 2
        for (int it = 0; it < 32; ++it) {
            const size_t base = (wi0 + it) * 256;       // int index
            int v0 = adj[base + ln];
            int v1 = adj[base + 64 + ln];
            int v2 = adj[base + 128 + ln];
            int v3 = adj[base + 192 + ln];
            unsigned long long b0 = __ballot(v0 > 0);
            unsigned long long b1 = __ballot(v1 > 0);
            unsigned long long b2 = __ballot(v2 > 0);
            unsigned long long b3 = __ballot(v3 > 0);
            if (ln < 8) {
                int c = ln >> 1;
                unsigned long long bb = (c == 0) ? b0 : (c == 1) ? b1 : (c == 2) ? b2 : b3;
                bits[(wi0 + it) * 8 + ln] = (unsigned)(bb >> ((ln & 1) * 32));
            }
        }
        return;
    }

    // ---- k1: 8 rows/block ----
    const int i0 = blockIdx.x * 8;
    #pragma unroll
    for (int u = 0; u < 2; ++u) {
        int idx = u * 256 + t;
        int r   = idx >> 6;               // 0..7 (wave-uniform)
        int kq  = idx & 63;
        *(float4*)&hs[r][kq * 4] = *(const float4*)(h + (size_t)(i0 + r) * INF + kq * 4);
    }
    __syncthreads();

    const int rg = t >> 5;                // 0..7 : row
    const int ct = t & 31;                // 0..31 : col group
    float acc[4] = {0.f, 0.f, 0.f, 0.f};

    #pragma unroll 8
    for (int k = 0; k < INF; ++k) {
        float4 wv = *(const float4*)(W + (size_t)k * OUTF + ct * 4);
        float  hx = hs[rg][k];
        acc[0] += hx * wv.x; acc[1] += hx * wv.y;
        acc[2] += hx * wv.z; acc[3] += hx * wv.w;
    }

    const int r0 = i0 + rg;               // j index
    const int jb = r0 >> 5;
    const int jo = r0 & 31;
    #pragma unroll
    for (int cc = 0; cc < 4; ++cc)
        WhTb[(size_t)jb * 4096 + (ct * 4 + cc) * 32 + jo] = f2bf(acc[cc]);

    const float4 a1v = *(const float4*)(a + ct * 4);
    const float4 a2v = *(const float4*)(a + OUTF + ct * 4);
    float p1 = acc[0]*a1v.x + acc[1]*a1v.y + acc[2]*a1v.z + acc[3]*a1v.w;
    float p2 = acc[0]*a2v.x + acc[1]*a2v.y + acc[2]*a2v.z + acc[3]*a2v.w;
    #pragma unroll
    for (int off = 16; off > 0; off >>= 1) {
        p1 += __shfl_down(p1, off, 32);
        p2 += __shfl_down(p2, off, 32);
    }
    if (ct == 0) { f1[r0] = p1; f2[r0] = p2; }
}

// ---------------- Kernel 2: MFMA attention + fused last-block combine --------
// One-pass masked softmax (exact vs ref; verified rounds 1-11). Grid (N/64,JS):
// 64 rows/block, 4 waves, 1024-j span, NTS=32 steps. Single-tile staging (r10's
// best structure): 8 KB B-tile per step via global_load_lds, LDS double buffer,
// 1 barrier/step. LDS 20.7 KB + __launch_bounds__(256,5) -> 5 blocks/CU =
// 20 waves/CU (vs 16): more TLP to fill the barrier-drain stall.
// Epilogue: last block per i-group (device-scope atomic counter, fenced)
// combines the JS partials and writes out — k3 launch eliminated.
__device__ __forceinline__ float pbit(float f1r, float fv, unsigned byte_,
                                      int u, float& dsum) {
    float s = f1r + fv;
    float e = fmaxf(s, ALPHA * s);        // leaky-relu, branch-free
    float p = (byte_ & (1u << u)) ? __expf(e) : 0.f;
    dsum += p;
    return p;
}

// PH = compile-time buffer phase (JT&1); stage JT+1 into PH^1, compute JT.
#define K2SUB(WORD, PH, JT)                                                  \
    {                                                                        \
        if ((JT) + 1 < NTS) {                                                \
            const char* ws_ = (const char*)WhTb + (size_t)(tile0 + (JT) + 1) * 8192; \
            char* bd_ = (char*)&bsm[(PH) ^ 1][0];                            \
            gll16(ws_ + t * 16,        bd_ + wv * 1024);                     \
            gll16(ws_ + 4096 + t * 16, bd_ + 4096 + wv * 1024);              \
        }                                                                    \
        float4 F0_ = *(const float4*)&f2s[(JT) * 32 + quad * 8];             \
        float4 F1_ = *(const float4*)&f2s[(JT) * 32 + quad * 8 + 4];         \
        unsigned byte_ = ((WORD) >> (quad << 3)) & 0xffu;                    \
        float p0_ = pbit(f1r, F0_.x, byte_, 0, dsum);                        \
        float p1_ = pbit(f1r, F0_.y, byte_, 1, dsum);                        \
        float p2_ = pbit(f1r, F0_.z, byte_, 2, dsum);                        \
        float p3_ = pbit(f1r, F0_.w, byte_, 3, dsum);                        \
        float p4_ = pbit(f1r, F1_.x, byte_, 4, dsum);                        \
        float p5_ = pbit(f1r, F1_.y, byte_, 5, dsum);                        \
        float p6_ = pbit(f1r, F1_.z, byte_, 6, dsum);                        \
        float p7_ = pbit(f1r, F1_.w, byte_, 7, dsum);                        \
        union { __hip_bfloat162 hh[4]; bf16x8 v; } pk_;                      \
        pk_.hh[0] = __float22bfloat162_rn(make_float2(p0_, p1_));            \
        pk_.hh[1] = __float22bfloat162_rn(make_float2(p2_, p3_));            \
        pk_.hh[2] = __float22bfloat162_rn(make_float2(p4_, p5_));            \
        pk_.hh[3] = __float22bfloat162_rn(make_float2(p6_, p7_));            \
        bf16x8 afrag = pk_.v;                                                \
        const char* bb_ = (const char*)&bsm[PH][0] + laneb2;                 \
        bf16x8 b0_ = *(const bf16x8*)(bb_);                                  \
        bf16x8 b1_ = *(const bf16x8*)(bb_ + 1024);                           \
        bf16x8 b2_ = *(const bf16x8*)(bb_ + 2048);                           \
        bf16x8 b3_ = *(const bf16x8*)(bb_ + 3072);                           \
        bf16x8 b4_ = *(const bf16x8*)(bb_ + 4096);                           \
        bf16x8 b5_ = *(const bf16x8*)(bb_ + 5120);                           \
        bf16x8 b6_ = *(const bf16x8*)(bb_ + 6144);                           \
        bf16x8 b7_ = *(const bf16x8*)(bb_ + 7168);                           \
        acc0 = __builtin_amdgcn_mfma_f32_16x16x32_bf16(afrag, b0_, acc0, 0, 0, 0); \
        acc1 = __builtin_amdgcn_mfma_f32_16x16x32_bf16(afrag, b1_, acc1, 0, 0, 0); \
        acc2 = __builtin_amdgcn_mfma_f32_16x16x32_bf16(afrag, b2_, acc2, 0, 0, 0); \
        acc3 = __builtin_amdgcn_mfma_f32_16x16x32_bf16(afrag, b3_, acc3, 0, 0, 0); \
        acc4 = __builtin_amdgcn_mfma_f32_16x16x32_bf16(afrag, b4_, acc4, 0, 0, 0); \
        acc5 = __builtin_amdgcn_mfma_f32_16x16x32_bf16(afrag, b5_, acc5, 0, 0, 0); \
        acc6 = __builtin_amdgcn_mfma_f32_16x16x32_bf16(afrag, b6_, acc6, 0, 0, 0); \
        acc7 = __builtin_amdgcn_mfma_f32_16x16x32_bf16(afrag, b7_, acc7, 0, 0, 0); \
        __syncthreads();                                                     \
    }

__global__ __launch_bounds__(256, 5) void k2_attn(
        const unsigned* __restrict__ bits, const unsigned short* __restrict__ WhTb,
        const float* __restrict__ f1, const float* __restrict__ f2,
        float* __restrict__ num, float* __restrict__ den,
        unsigned* __restrict__ cnt, float* __restrict__ out) {
    __shared__ unsigned short bsm[2][4096];   // 2 x 8 KB B-tile double buffer
    __shared__ float f2s[1024];               // block's f2 span (4 KB)
    __shared__ int   lastf;
    __shared__ float dls[64];

    const int t    = threadIdx.x;
    const int wv   = t >> 6;              // 0..3 : wave -> row-tile
    const int ln   = t & 63;
    const int m16  = ln & 15;
    const int quad = ln >> 4;
    const int i0   = blockIdx.x * 64;
    const int s    = blockIdx.y;
    const int row  = i0 + wv * 16 + m16;
    const int tile0 = s * NTS;
    const int j0    = s * (N / JS);
    const int laneb2 = (m16 * 32 + quad * 8) * 2;   // byte offset in 8 KB tile

    // stage f2 span + B tile 0 (async)
    *(float4*)&f2s[t * 4] = *(const float4*)(f2 + j0 + t * 4);
    {
        const char* ws0 = (const char*)WhTb + (size_t)tile0 * 8192;
        char* bd = (char*)&bsm[0][0];
        gll16(ws0 + t * 16,        bd + wv * 1024);
        gll16(ws0 + 4096 + t * 16, bd + 4096 + wv * 1024);
    }

    const float f1r = f1[row];
    const uint4* brow = (const uint4*)(bits + (size_t)row * 256 + tile0);

    f32x4 acc0 = {0.f,0.f,0.f,0.f}, acc1 = {0.f,0.f,0.f,0.f};
    f32x4 acc2 = {0.f,0.f,0.f,0.f}, acc3 = {0.f,0.f,0.f,0.f};
    f32x4 acc4 = {0.f,0.f,0.f,0.f}, acc5 = {0.f,0.f,0.f,0.f};
    f32x4 acc6 = {0.f,0.f,0.f,0.f}, acc7 = {0.f,0.f,0.f,0.f};
    float dsum = 0.f;

    uint4 bwc = brow[0];                  // bits prefetch (L2-hot)
    __syncthreads();                      // f2s + bsm[0] ready (drains vmcnt)

    for (int g = 0; g < NTS / 4; ++g) {   // 8 groups x 4 steps
        uint4 bwn = brow[(g + 1 < NTS / 4) ? g + 1 : g];
        const int jtb = g * 4;
        K2SUB(bwc.x, 0, jtb + 0)
        K2SUB(bwc.y, 1, jtb + 1)
        K2SUB(bwc.z, 0, jtb + 2)
        K2SUB(bwc.w, 1, jtb + 3)
        bwc = bwn;
    }

    // den partial: sum the 4 quads of each row
    dsum += __shfl_xor(dsum, 16);
    dsum += __shfl_xor(dsum, 32);
    if (quad == 0) den[(size_t)s * N + row] = dsum;

    // num partial: D layout col=lane&15, row=quad*4+reg
    float* np = num + (size_t)s * N * OUTF;
    #pragma unroll
    for (int r = 0; r < 4; ++r) {
        const size_t orow = (size_t)(i0 + wv * 16 + quad * 4 + r) * OUTF;
        np[orow + 0 * 16 + m16] = acc0[r];
        np[orow + 1 * 16 + m16] = acc1[r];
        np[orow + 2 * 16 + m16] = acc2[r];
        np[orow + 3 * 16 + m16] = acc3[r];
        np[orow + 4 * 16 + m16] = acc4[r];
        np[orow + 5 * 16 + m16] = acc5[r];
        np[orow + 6 * 16 + m16] = acc6[r];
        np[orow + 7 * 16 + m16] = acc7[r];
    }

    // ---- fused combine: last block of this i-group merges the JS partials ----
    __threadfence();                      // release our partials (device scope)
    __syncthreads();
    if (t == 0) lastf = (atomicAdd(&cnt[blockIdx.x], 1u) == JS - 1);
    __syncthreads();
    if (!lastf) return;
    __threadfence();                      // acquire other blocks' partials

    if (t < 64) {
        float d = 0.f;
        #pragma unroll
        for (int s2 = 0; s2 < JS; ++s2) d += den[(size_t)s2 * N + i0 + t];
        dls[t] = 1.0f / d;
    }
    __syncthreads();

    #pragma unroll
    for (int e = 0; e < 8; ++e) {
        int idx = e * 256 + t;            // 2048 float4 = 64 rows x 128 cols
        int r   = idx >> 5;               // 0..63
        int c4  = (idx & 31) * 4;
        float4 ns = {0.f,0.f,0.f,0.f};
        #pragma unroll
        for (int s2 = 0; s2 < JS; ++s2) {
            float4 v = *(const float4*)(num + ((size_t)s2 * N + i0 + r) * OUTF + c4);
            ns.x += v.x; ns.y += v.y; ns.z += v.z; ns.w += v.w;
        }
        const float inv = dls[r];
        float4 o = {ns.x * inv, ns.y * inv, ns.z * inv, ns.w * inv};
        *(float4*)(out + (size_t)(i0 + r) * OUTF + c4) = o;
    }
}

extern "C" void kernel_launch(void* const* d_in, const int* in_sizes, int n_in,
                              void* d_out, int out_size, void* d_ws, size_t ws_size,
                              hipStream_t stream) {
    const float* h   = (const float*)d_in[0];   // (8192, 256)
    const int*   adj = (const int*)  d_in[1];   // (8192, 8192)
    const float* W   = (const float*)d_in[2];   // (256, 128)
    const float* a   = (const float*)d_in[3];   // (256, 1)
    float* out = (float*)d_out;                 // (8192, 128)

    unsigned short* WhTb = (unsigned short*)d_ws;          // 2 MB blocked bf16
    float*    f1   = (float*)(WhTb + (size_t)N * OUTF);    // 32 KB
    float*    f2   = f1 + N;                               // 32 KB
    float*    den  = f2 + N;                               // JS*N = 256 KB
    unsigned* bits = (unsigned*)(den + (size_t)JS * N);    // 8 MB
    float*    num  = (float*)(bits + (size_t)N * (N / 32));// JS*N*OUTF = 32 MB
    unsigned* cnt  = (unsigned*)(num + (size_t)JS * N * OUTF);  // 512 B

    hipMemsetAsync(cnt, 0, (N / 64) * sizeof(unsigned), stream);
    k01_prep<<<1024 + 2048, 256, 0, stream>>>(adj, bits, h, W, a, WhTb, f1, f2);
    k2_attn <<<dim3(N / 64, JS), 256, 0, stream>>>(bits, WhTb, f1, f2, num, den, cnt, out);
}

// Round 13
// 434.890 us; speedup vs baseline: 1.3131x; 1.3131x over previous
//
#include <hip/hip_runtime.h>
#include <hip/hip_bf16.h>

#define N    8192
#define INF  256
#define OUTF 128
#define ALPHA 0.2f
#define JS   8               // j-split across blockIdx.y
#define NTS  (N / JS / 32)   // 32 K-steps per block

typedef __attribute__((ext_vector_type(8))) short bf16x8;
typedef __attribute__((ext_vector_type(4))) float f32x4;

__device__ __forceinline__ unsigned short f2bf(float x) {
    union { float f; unsigned u; } v; v.f = x;
    unsigned r = v.u + 0x7fff + ((v.u >> 16) & 1);   // RNE
    return (unsigned short)(r >> 16);
}

// async global->LDS, 16 B per lane (wave-uniform LDS base + lane*16)
__device__ __forceinline__ void gll16(const void* g, void* l) {
    __builtin_amdgcn_global_load_lds(
        (const __attribute__((address_space(1))) unsigned*)g,
        (__attribute__((address_space(3))) unsigned*)l, 16, 0, 0);
}

// ---------------- Kernel 0+1 fused (r10 structure, best-known) ---------------
// Blocks [0,1024): k1 body — WhT_b = blocked bf16 (h@W)^T ; f1 ; f2.
// Blocks [1024,9216): k0 body — bit-pack adj (268 MB -> 8 MB).
__global__ __launch_bounds__(256) void k01_prep(
        const int* __restrict__ adj, unsigned* __restrict__ bits,
        const float* __restrict__ h, const float* __restrict__ W,
        const float* __restrict__ a,
        unsigned short* __restrict__ WhTb, float* __restrict__ f1, float* __restrict__ f2) {
    __shared__ float hs[8][INF];          // 8 KB (k1 blocks only)
    const int t = threadIdx.x;

    if (blockIdx.x >= 1024) {
        // ---- k0: pack 32 adj ints -> 1 bit word per thread (L1 merges) ----
        const size_t g = (size_t)(blockIdx.x - 1024) * 256 + t;   // word idx, 2M
        const int4* p = (const int4*)adj + g * 8;
        unsigned b = 0;
        #pragma unroll
        for (int u = 0; u < 8; ++u) {
            int4 v = p[u];
            b |= (v.x > 0 ? 1u : 0u) << (u * 4 + 0);
            b |= (v.y > 0 ? 1u : 0u) << (u * 4 + 1);
            b |= (v.z > 0 ? 1u : 0u) << (u * 4 + 2);
            b |= (v.w > 0 ? 1u : 0u) << (u * 4 + 3);
        }
        bits[g] = b;
        return;
    }

    // ---- k1: 8 rows/block ----
    const int i0 = blockIdx.x * 8;
    #pragma unroll
    for (int u = 0; u < 2; ++u) {
        int idx = u * 256 + t;
        int r   = idx >> 6;               // 0..7 (wave-uniform)
        int kq  = idx & 63;
        *(float4*)&hs[r][kq * 4] = *(const float4*)(h + (size_t)(i0 + r) * INF + kq * 4);
    }
    __syncthreads();

    const int rg = t >> 5;                // 0..7 : row
    const int ct = t & 31;                // 0..31 : col group
    float acc[4] = {0.f, 0.f, 0.f, 0.f};

    #pragma unroll 8
    for (int k = 0; k < INF; ++k) {
        float4 wv = *(const float4*)(W + (size_t)k * OUTF + ct * 4);
        float  hx = hs[rg][k];
        acc[0] += hx * wv.x; acc[1] += hx * wv.y;
        acc[2] += hx * wv.z; acc[3] += hx * wv.w;
    }

    const int r0 = i0 + rg;               // j index
    const int jb = r0 >> 5;
    const int jo = r0 & 31;
    #pragma unroll
    for (int cc = 0; cc < 4; ++cc)
        WhTb[(size_t)jb * 4096 + (ct * 4 + cc) * 32 + jo] = f2bf(acc[cc]);

    const float4 a1v = *(const float4*)(a + ct * 4);
    const float4 a2v = *(const float4*)(a + OUTF + ct * 4);
    float p1 = acc[0]*a1v.x + acc[1]*a1v.y + acc[2]*a1v.z + acc[3]*a1v.w;
    float p2 = acc[0]*a2v.x + acc[1]*a2v.y + acc[2]*a2v.z + acc[3]*a2v.w;
    #pragma unroll
    for (int off = 16; off > 0; off >>= 1) {
        p1 += __shfl_down(p1, off, 32);
        p2 += __shfl_down(p2, off, 32);
    }
    if (ct == 0) { f1[r0] = p1; f2[r0] = p2; }
}

// ---------------- Kernel 2: MFMA attention, 128 rows/block -------------------
// One-pass masked softmax (exact vs ref; verified rounds 1-12). Grid (N/128,JS)
// = 512 blocks, 512 threads (8 waves x 16 rows = 128 rows/block), 1024-j span,
// NTS=32 steps. The SAME 8 KB B-tile per step now feeds 2x the MFMA work ->
// per-CU barrier-drain count halves vs r10 (the measured ~85% stall component).
// Staging: exactly one global_load_lds per thread per step, LDS double buffer,
// one barrier/step. Bits: L2-hot uint4 per 4 steps. 2 blocks/CU, 16 waves/CU.
__device__ __forceinline__ float pbit(float f1r, float fv, unsigned byte_,
                                      int u, float& dsum) {
    float s = f1r + fv;
    float e = fmaxf(s, ALPHA * s);        // leaky-relu, branch-free
    float p = (byte_ & (1u << u)) ? __expf(e) : 0.f;
    dsum += p;
    return p;
}

// PH = compile-time buffer phase (JT&1); stage JT+1 into PH^1, compute JT.
#define K2SUB(WORD, PH, JT)                                                  \
    {                                                                        \
        if ((JT) + 1 < NTS) {                                                \
            const char* ws_ = (const char*)WhTb + (size_t)(tile0 + (JT) + 1) * 8192; \
            gll16(ws_ + t * 16, (char*)&bsm[(PH) ^ 1][0] + wv * 1024);       \
        }                                                                    \
        float4 F0_ = *(const float4*)&f2s[(JT) * 32 + quad * 8];             \
        float4 F1_ = *(const float4*)&f2s[(JT) * 32 + quad * 8 + 4];         \
        unsigned byte_ = ((WORD) >> (quad << 3)) & 0xffu;                    \
        float p0_ = pbit(f1r, F0_.x, byte_, 0, dsum);                        \
        float p1_ = pbit(f1r, F0_.y, byte_, 1, dsum);                        \
        float p2_ = pbit(f1r, F0_.z, byte_, 2, dsum);                        \
        float p3_ = pbit(f1r, F0_.w, byte_, 3, dsum);                        \
        float p4_ = pbit(f1r, F1_.x, byte_, 4, dsum);                        \
        float p5_ = pbit(f1r, F1_.y, byte_, 5, dsum);                        \
        float p6_ = pbit(f1r, F1_.z, byte_, 6, dsum);                        \
        float p7_ = pbit(f1r, F1_.w, byte_, 7, dsum);                        \
        union { __hip_bfloat162 hh[4]; bf16x8 v; } pk_;                      \
        pk_.hh[0] = __float22bfloat162_rn(make_float2(p0_, p1_));            \
        pk_.hh[1] = __float22bfloat162_rn(make_float2(p2_, p3_));            \
        pk_.hh[2] = __float22bfloat162_rn(make_float2(p4_, p5_));            \
        pk_.hh[3] = __float22bfloat162_rn(make_float2(p6_, p7_));            \
        bf16x8 afrag = pk_.v;                                                \
        const char* bb_ = (const char*)&bsm[PH][0] + laneb2;                 \
        bf16x8 b0_ = *(const bf16x8*)(bb_);                                  \
        bf16x8 b1_ = *(const bf16x8*)(bb_ + 1024);                           \
        bf16x8 b2_ = *(const bf16x8*)(bb_ + 2048);                           \
        bf16x8 b3_ = *(const bf16x8*)(bb_ + 3072);                           \
        bf16x8 b4_ = *(const bf16x8*)(bb_ + 4096);                           \
        bf16x8 b5_ = *(const bf16x8*)(bb_ + 5120);                           \
        bf16x8 b6_ = *(const bf16x8*)(bb_ + 6144);                           \
        bf16x8 b7_ = *(const bf16x8*)(bb_ + 7168);                           \
        acc0 = __builtin_amdgcn_mfma_f32_16x16x32_bf16(afrag, b0_, acc0, 0, 0, 0); \
        acc1 = __builtin_amdgcn_mfma_f32_16x16x32_bf16(afrag, b1_, acc1, 0, 0, 0); \
        acc2 = __builtin_amdgcn_mfma_f32_16x16x32_bf16(afrag, b2_, acc2, 0, 0, 0); \
        acc3 = __builtin_amdgcn_mfma_f32_16x16x32_bf16(afrag, b3_, acc3, 0, 0, 0); \
        acc4 = __builtin_amdgcn_mfma_f32_16x16x32_bf16(afrag, b4_, acc4, 0, 0, 0); \
        acc5 = __builtin_amdgcn_mfma_f32_16x16x32_bf16(afrag, b5_, acc5, 0, 0, 0); \
        acc6 = __builtin_amdgcn_mfma_f32_16x16x32_bf16(afrag, b6_, acc6, 0, 0, 0); \
        acc7 = __builtin_amdgcn_mfma_f32_16x16x32_bf16(afrag, b7_, acc7, 0, 0, 0); \
        __syncthreads();                                                     \
    }

__global__ __launch_bounds__(512, 4) void k2_attn(
        const unsigned* __restrict__ bits, const unsigned short* __restrict__ WhTb,
        const float* __restrict__ f1, const float* __restrict__ f2,
        float* __restrict__ num, float* __restrict__ den) {
    __shared__ unsigned short bsm[2][4096];   // 2 x 8 KB B-tile double buffer
    __shared__ float f2s[1024];               // block's f2 span (4 KB)

    const int t    = threadIdx.x;             // 0..511
    const int wv   = t >> 6;                  // 0..7 : wave -> row-tile
    const int ln   = t & 63;
    const int m16  = ln & 15;
    const int quad = ln >> 4;
    const int i0   = blockIdx.x * 128;
    const int s    = blockIdx.y;
    const int row  = i0 + wv * 16 + m16;
    const int tile0 = s * NTS;
    const int j0    = s * (N / JS);
    const int laneb2 = (m16 * 32 + quad * 8) * 2;   // byte offset in 8 KB tile

    // stage f2 span + B tile 0 (one gll16/thread covers the full 8 KB)
    if (t < 256) *(float4*)&f2s[t * 4] = *(const float4*)(f2 + j0 + t * 4);
    gll16((const char*)WhTb + (size_t)tile0 * 8192 + t * 16,
          (char*)&bsm[0][0] + wv * 1024);

    const float f1r = f1[row];
    const uint4* brow = (const uint4*)(bits + (size_t)row * 256 + tile0);

    f32x4 acc0 = {0.f,0.f,0.f,0.f}, acc1 = {0.f,0.f,0.f,0.f};
    f32x4 acc2 = {0.f,0.f,0.f,0.f}, acc3 = {0.f,0.f,0.f,0.f};
    f32x4 acc4 = {0.f,0.f,0.f,0.f}, acc5 = {0.f,0.f,0.f,0.f};
    f32x4 acc6 = {0.f,0.f,0.f,0.f}, acc7 = {0.f,0.f,0.f,0.f};
    float dsum = 0.f;

    uint4 bwc = brow[0];                  // bits prefetch (L2-hot)
    __syncthreads();                      // f2s + bsm[0] ready (drains vmcnt)

    for (int g = 0; g < NTS / 4; ++g) {   // 8 groups x 4 steps
        uint4 bwn = brow[(g + 1 < NTS / 4) ? g + 1 : g];
        const int jtb = g * 4;
        K2SUB(bwc.x, 0, jtb + 0)
        K2SUB(bwc.y, 1, jtb + 1)
        K2SUB(bwc.z, 0, jtb + 2)
        K2SUB(bwc.w, 1, jtb + 3)
        bwc = bwn;
    }

    // den partial: sum the 4 quads of each row
    dsum += __shfl_xor(dsum, 16);
    dsum += __shfl_xor(dsum, 32);
    if (quad == 0) den[(size_t)s * N + row] = dsum;

    // num partial: D layout col=lane&15, row=quad*4+reg
    float* np = num + (size_t)s * N * OUTF;
    #pragma unroll
    for (int r = 0; r < 4; ++r) {
        const size_t orow = (size_t)(i0 + wv * 16 + quad * 4 + r) * OUTF;
        np[orow + 0 * 16 + m16] = acc0[r];
        np[orow + 1 * 16 + m16] = acc1[r];
        np[orow + 2 * 16 + m16] = acc2[r];
        np[orow + 3 * 16 + m16] = acc3[r];
        np[orow + 4 * 16 + m16] = acc4[r];
        np[orow + 5 * 16 + m16] = acc5[r];
        np[orow + 6 * 16 + m16] = acc6[r];
        np[orow + 7 * 16 + m16] = acc7[r];
    }
}

// ---------------- Kernel 3: combine JS partials, normalize ----------------
__global__ __launch_bounds__(256) void k3_combine(
        const float* __restrict__ num, const float* __restrict__ den,
        float* __restrict__ out) {
    const int idx = blockIdx.x * 256 + threadIdx.x;   // float4 index
    const int row = idx >> 5;
    const int c4  = (idx & 31) * 4;
    float4 ns = {0.f,0.f,0.f,0.f};
    float  ds = 0.f;
    #pragma unroll
    for (int s = 0; s < JS; ++s) {
        float4 nv = *(const float4*)(num + ((size_t)s * N + row) * OUTF + c4);
        ns.x += nv.x; ns.y += nv.y; ns.z += nv.z; ns.w += nv.w;
        ds += den[(size_t)s * N + row];
    }
    const float inv = 1.0f / ds;
    float4 o = {ns.x * inv, ns.y * inv, ns.z * inv, ns.w * inv};
    *(float4*)(out + (size_t)row * OUTF + c4) = o;
}

extern "C" void kernel_launch(void* const* d_in, const int* in_sizes, int n_in,
                              void* d_out, int out_size, void* d_ws, size_t ws_size,
                              hipStream_t stream) {
    const float* h   = (const float*)d_in[0];   // (8192, 256)
    const int*   adj = (const int*)  d_in[1];   // (8192, 8192)
    const float* W   = (const float*)d_in[2];   // (256, 128)
    const float* a   = (const float*)d_in[3];   // (256, 1)
    float* out = (float*)d_out;                 // (8192, 128)

    unsigned short* WhTb = (unsigned short*)d_ws;          // 2 MB blocked bf16
    float*    f1   = (float*)(WhTb + (size_t)N * OUTF);    // 32 KB
    float*    f2   = f1 + N;                               // 32 KB
    float*    den  = f2 + N;                               // JS*N = 256 KB
    unsigned* bits = (unsigned*)(den + (size_t)JS * N);    // 8 MB
    float*    num  = (float*)(bits + (size_t)N * (N / 32));// JS*N*OUTF = 32 MB

    k01_prep  <<<1024 + (N / 32) * (N / 256), 256, 0, stream>>>(adj, bits, h, W, a, WhTb, f1, f2);
    k2_attn   <<<dim3(N / 128, JS), 512, 0, stream>>>(bits, WhTb, f1, f2, num, den);
    k3_combine<<<(N * OUTF / 4) / 256, 256, 0, stream>>>(num, den, out);
}